// Round 1
// baseline (186.721 us; speedup 1.0000x reference)
//
#include <hip/hip_runtime.h>
#include <hip/hip_fp16.h>
#include <stdint.h>

// Problem constants (B,C_IN,L fixed by the reference)
#define BB    4
#define CIN   512
#define CRED  256
#define LL    16384
#define NBLK  256      // L / 64
#define WELEM 131072   // elements per weight matrix (256*512)

typedef _Float16 half8 __attribute__((ext_vector_type(8)));
typedef float    f32x4 __attribute__((ext_vector_type(4)));

// ---------------- LDS byte layout (160 KB dynamic) ----------------
// Phase 1-2:  XT  [64 pos][512 ch] fp16, row stride 1024 B, swizzled   0..65536
// Phase 2+ :  Q   [64 pos][256 ch] fp16, row 512 B                     65536..98304
//             K   [64 pos][256 ch] fp16, row 512 B                     98304..131072
//             V   [256 ch][64 pos] fp16, row 128 B                     131072..163840
// After QKV consumed, XT region is reused:
//             S   [64][64] f32, row 256 B                              0..16384
//             P   [64 i][64 j] fp16, row 128 B                         16384..24576
//             H   [64 pos][256 ch] fp16, row 512 B                     24576..57344
#define XT_OFF 0
#define S_OFF  0
#define P_OFF  16384
#define H_OFF  24576
#define Q_OFF  65536
#define K_OFF  98304
#define V_OFF  131072
#define LDS_BYTES 163840

// XOR swizzle: spread 16-B fragment reads of different rows across banks.
// All row strides are multiples of 128 B; G(row) = (row&7)<<4 keeps 16-B
// granularity (safe for ds_read_b128) and stays within every row.
#define SWZ(row) (((row) & 7) << 4)

__global__ void convert_weights(const float* __restrict__ Wq,
                                const float* __restrict__ Wk,
                                const float* __restrict__ Wv,
                                const float* __restrict__ Wo,
                                _Float16* __restrict__ dst) {
    int i = blockIdx.x * blockDim.x + threadIdx.x;   // 0 .. 4*131072-1
    int m = i >> 17;
    int e = i & (WELEM - 1);
    const float* src = (m == 0) ? Wq : (m == 1) ? Wk : (m == 2) ? Wv : Wo;
    dst[(size_t)m * WELEM + e] = (_Float16)src[e];
}

__global__ __launch_bounds__(512, 2)
void att_fused(const float* __restrict__ x1, const float* __restrict__ mask,
               const _Float16* __restrict__ W,
               const float* __restrict__ bq, const float* __restrict__ bk,
               const float* __restrict__ bv, const float* __restrict__ bo,
               float* __restrict__ out) {
    extern __shared__ char lds[];
    const int tid  = threadIdx.x;
    const int wid  = tid >> 6;
    const int lane = tid & 63;
    const int l15  = lane & 15;
    const int l4   = lane >> 4;
    const int blk  = blockIdx.x;
    const int b    = blk >> 8;     // batch
    const int n    = blk & 255;    // 64-pos block index

    const _Float16* Wq = W;
    const _Float16* Wk = W + WELEM;
    const _Float16* Wv = W + 2 * WELEM;
    const _Float16* Wo = W + 3 * WELEM;

    // -------- Phase 1: stage X^T (pos-major, ch contiguous) into LDS --------
    // thread t: channel-pair p = t&255 (c = 2p, 2p+1); j-half = t>>8.
    // Global: 16-B reads per row, rows L1-cached across the 8 j-group iters.
    // LDS: ds_write_b32 pairs, ~2 lanes/bank (free).
    {
        const int p  = tid & 255;
        const int hs = tid >> 8;
        const float* r0 = x1 + ((size_t)b * CIN + 2 * p) * LL + n * 64;
        const float* r1 = r0 + LL;
        #pragma unroll
        for (int g8 = 0; g8 < 8; ++g8) {
            const int g = hs * 8 + g8;
            f32x4 a = *(const f32x4*)(r0 + 4 * g);
            f32x4 c = *(const f32x4*)(r1 + 4 * g);
            #pragma unroll
            for (int u = 0; u < 4; ++u) {
                const int j = 4 * g + u;
                union { _Float16 h[2]; uint32_t w; } pk;
                pk.h[0] = (_Float16)a[u];
                pk.h[1] = (_Float16)c[u];
                *(uint32_t*)(lds + XT_OFF + j * 1024 + ((4 * p) ^ SWZ(j))) = pk.w;
            }
        }
    }
    __syncthreads();

    // -------- Phase 2: Q,K,V = W @ X  (M=256, K=512, N=64) --------
    // wave owns 32 output channels (2 m-tiles); A-frags stream from L2 weights.
    {
        const int mb = wid * 32;
        f32x4 acc[3][2][4];
        #pragma unroll
        for (int p = 0; p < 3; ++p)
            #pragma unroll
            for (int m = 0; m < 2; ++m)
                #pragma unroll
                for (int nt = 0; nt < 4; ++nt) acc[p][m][nt] = (f32x4){0.f, 0.f, 0.f, 0.f};

        #pragma unroll 4
        for (int ks = 0; ks < 16; ++ks) {
            const int k0 = ks * 32;
            const int kb = 2 * (k0 + l4 * 8);   // byte offset within row
            half8 xb[4];
            #pragma unroll
            for (int nt = 0; nt < 4; ++nt) {
                const int j = nt * 16 + l15;
                xb[nt] = *(const half8*)(lds + XT_OFF + j * 1024 + (kb ^ SWZ(j)));
            }
            #pragma unroll
            for (int mt = 0; mt < 2; ++mt) {
                const size_t off = (size_t)(mb + mt * 16 + l15) * CIN + k0 + l4 * 8;
                half8 aq = *(const half8*)(Wq + off);
                half8 ak = *(const half8*)(Wk + off);
                half8 av = *(const half8*)(Wv + off);
                #pragma unroll
                for (int nt = 0; nt < 4; ++nt) {
                    acc[0][mt][nt] = __builtin_amdgcn_mfma_f32_16x16x32_f16(aq, xb[nt], acc[0][mt][nt], 0, 0, 0);
                    acc[1][mt][nt] = __builtin_amdgcn_mfma_f32_16x16x32_f16(ak, xb[nt], acc[1][mt][nt], 0, 0, 0);
                    acc[2][mt][nt] = __builtin_amdgcn_mfma_f32_16x16x32_f16(av, xb[nt], acc[2][mt][nt], 0, 0, 0);
                }
            }
        }
        // epilogue: +bias, fp16, scatter to LDS. Q,K as [pos][ch]; V as [ch][pos].
        #pragma unroll
        for (int mt = 0; mt < 2; ++mt) {
            #pragma unroll
            for (int ri = 0; ri < 4; ++ri) {
                const int c = mb + mt * 16 + l4 * 4 + ri;
                const float bqv = bq[c], bkv = bk[c], bvv = bv[c];
                #pragma unroll
                for (int nt = 0; nt < 4; ++nt) {
                    const int j = nt * 16 + l15;
                    *(_Float16*)(lds + Q_OFF + j * 512 + ((2 * c) ^ SWZ(j))) =
                        (_Float16)(acc[0][mt][nt][ri] + bqv);
                    *(_Float16*)(lds + K_OFF + j * 512 + ((2 * c) ^ SWZ(j))) =
                        (_Float16)(acc[1][mt][nt][ri] + bkv);
                    *(_Float16*)(lds + V_OFF + c * 128 + ((2 * j) ^ SWZ(c))) =
                        (_Float16)(acc[2][mt][nt][ri] + bvv);
                }
            }
        }
    }
    __syncthreads();

    // -------- Phase 3: S = (Q^T K) * scale  (64x64, K=256) --------
    // wave: i0 = (w&3)*16, two j-tiles at (w>>2)*32.
    {
        const int i0 = (wid & 3) * 16;
        const int j0 = (wid >> 2) * 32;
        f32x4 sa0 = (f32x4){0.f, 0.f, 0.f, 0.f};
        f32x4 sa1 = (f32x4){0.f, 0.f, 0.f, 0.f};
        #pragma unroll
        for (int ks = 0; ks < 8; ++ks) {
            const int kb = 2 * (ks * 32 + l4 * 8);
            const int iq = i0 + l15;
            const int ja = j0 + l15;
            const int jb = j0 + 16 + l15;
            half8 qa = *(const half8*)(lds + Q_OFF + iq * 512 + (kb ^ SWZ(iq)));
            half8 k0f = *(const half8*)(lds + K_OFF + ja * 512 + (kb ^ SWZ(ja)));
            half8 k1f = *(const half8*)(lds + K_OFF + jb * 512 + (kb ^ SWZ(jb)));
            sa0 = __builtin_amdgcn_mfma_f32_16x16x32_f16(qa, k0f, sa0, 0, 0, 0);
            sa1 = __builtin_amdgcn_mfma_f32_16x16x32_f16(qa, k1f, sa1, 0, 0, 0);
        }
        #pragma unroll
        for (int ri = 0; ri < 4; ++ri) {
            const int i = i0 + l4 * 4 + ri;
            *(float*)(lds + S_OFF + i * 256 + 4 * (j0 + l15))      = sa0[ri] * 0.0625f;
            *(float*)(lds + S_OFF + i * 256 + 4 * (j0 + 16 + l15)) = sa1[ri] * 0.0625f;
        }
    }
    __syncthreads();

    // -------- Phase 4: masked softmax over j, write P [i][j] fp16 --------
    // 8 threads per row, 8 cols each; shfl_xor reduction within the 8-group.
    {
        const int r   = tid >> 3;
        const int sub = tid & 7;
        const float* mrow = mask + (size_t)b * LL + n * 64;
        f32x4 s0 = *(const f32x4*)(lds + S_OFF + r * 256 + sub * 32);
        f32x4 s1 = *(const f32x4*)(lds + S_OFF + r * 256 + sub * 32 + 16);
        f32x4 m0 = *(const f32x4*)(mrow + sub * 8);
        f32x4 m1 = *(const f32x4*)(mrow + sub * 8 + 4);
        float v[8];
        #pragma unroll
        for (int u = 0; u < 4; ++u) {
            v[u]     = (m0[u] == 0.f) ? -1e30f : s0[u];
            v[u + 4] = (m1[u] == 0.f) ? -1e30f : s1[u];
        }
        float mx = v[0];
        #pragma unroll
        for (int u = 1; u < 8; ++u) mx = fmaxf(mx, v[u]);
        mx = fmaxf(mx, __shfl_xor(mx, 1));
        mx = fmaxf(mx, __shfl_xor(mx, 2));
        mx = fmaxf(mx, __shfl_xor(mx, 4));
        float e[8], sum = 0.f;
        #pragma unroll
        for (int u = 0; u < 8; ++u) { e[u] = __expf(v[u] - mx); sum += e[u]; }
        sum += __shfl_xor(sum, 1);
        sum += __shfl_xor(sum, 2);
        sum += __shfl_xor(sum, 4);
        const float inv = 1.f / sum;
        union { _Float16 h[8]; half8 v8; } pk;
        #pragma unroll
        for (int u = 0; u < 8; ++u) pk.h[u] = (_Float16)(e[u] * inv);
        *(half8*)(lds + P_OFF + r * 128 + ((sub * 16) ^ SWZ(r))) = pk.v8;
    }
    __syncthreads();

    // -------- Phase 5: H = relu(V @ P^T)  (M=256 ch, N=64 i, K=64 j) --------
    {
        const int cb = wid * 32;
        f32x4 pv[2][4];
        #pragma unroll
        for (int m = 0; m < 2; ++m)
            #pragma unroll
            for (int nt = 0; nt < 4; ++nt) pv[m][nt] = (f32x4){0.f, 0.f, 0.f, 0.f};
        #pragma unroll
        for (int ks = 0; ks < 2; ++ks) {
            const int kb = 2 * (ks * 32 + l4 * 8);
            half8 pb[4];
            #pragma unroll
            for (int nt = 0; nt < 4; ++nt) {
                const int i = nt * 16 + l15;
                pb[nt] = *(const half8*)(lds + P_OFF + i * 128 + (kb ^ SWZ(i)));
            }
            #pragma unroll
            for (int mt = 0; mt < 2; ++mt) {
                const int c = cb + mt * 16 + l15;
                half8 va = *(const half8*)(lds + V_OFF + c * 128 + (kb ^ SWZ(c)));
                #pragma unroll
                for (int nt = 0; nt < 4; ++nt)
                    pv[mt][nt] = __builtin_amdgcn_mfma_f32_16x16x32_f16(va, pb[nt], pv[mt][nt], 0, 0, 0);
            }
        }
        // relu + write H as [pos][ch] for the output GEMM
        #pragma unroll
        for (int mt = 0; mt < 2; ++mt) {
            #pragma unroll
            for (int ri = 0; ri < 4; ++ri) {
                const int c = cb + mt * 16 + l4 * 4 + ri;
                #pragma unroll
                for (int nt = 0; nt < 4; ++nt) {
                    const int i = nt * 16 + l15;
                    *(_Float16*)(lds + H_OFF + i * 512 + ((2 * c) ^ SWZ(i))) =
                        (_Float16)fmaxf(pv[mt][nt][ri], 0.f);
                }
            }
        }
    }
    __syncthreads();

    // -------- Phase 6: Out = Wo @ H + bo  (M=512, K=256, N=64) --------
    {
        const int mb = wid * 64;
        f32x4 oa[4][4];
        #pragma unroll
        for (int m = 0; m < 4; ++m)
            #pragma unroll
            for (int nt = 0; nt < 4; ++nt) oa[m][nt] = (f32x4){0.f, 0.f, 0.f, 0.f};
        #pragma unroll 4
        for (int ks = 0; ks < 8; ++ks) {
            const int k0 = ks * 32;
            const int kb = 2 * (k0 + l4 * 8);
            half8 hb[4];
            #pragma unroll
            for (int nt = 0; nt < 4; ++nt) {
                const int i = nt * 16 + l15;
                hb[nt] = *(const half8*)(lds + H_OFF + i * 512 + (kb ^ SWZ(i)));
            }
            #pragma unroll
            for (int mt = 0; mt < 4; ++mt) {
                const size_t off = (size_t)(mb + mt * 16 + l15) * CRED + k0 + l4 * 8;
                half8 wa = *(const half8*)(Wo + off);
                #pragma unroll
                for (int nt = 0; nt < 4; ++nt)
                    oa[mt][nt] = __builtin_amdgcn_mfma_f32_16x16x32_f16(wa, hb[nt], oa[mt][nt], 0, 0, 0);
            }
        }
        #pragma unroll
        for (int mt = 0; mt < 4; ++mt) {
            #pragma unroll
            for (int ri = 0; ri < 4; ++ri) {
                const int o = mb + mt * 16 + l4 * 4 + ri;
                const float bov = bo[o];
                float* orow = out + ((size_t)b * CIN + o) * LL + n * 64;
                #pragma unroll
                for (int nt = 0; nt < 4; ++nt)
                    orow[nt * 16 + l15] = oa[mt][nt][ri] + bov;
            }
        }
    }
}

extern "C" void kernel_launch(void* const* d_in, const int* in_sizes, int n_in,
                              void* d_out, int out_size, void* d_ws, size_t ws_size,
                              hipStream_t stream) {
    const float* x1   = (const float*)d_in[0];
    // d_in[1] = x2 : unused by the reference
    const float* mask = (const float*)d_in[2];
    const float* Wq   = (const float*)d_in[3];
    const float* bq   = (const float*)d_in[4];
    const float* Wk   = (const float*)d_in[5];
    const float* bk   = (const float*)d_in[6];
    const float* Wv   = (const float*)d_in[7];
    const float* bv   = (const float*)d_in[8];
    const float* Wo   = (const float*)d_in[9];
    const float* bo   = (const float*)d_in[10];
    float* out = (float*)d_out;
    _Float16* wbuf = (_Float16*)d_ws;   // 1 MB of fp16 weights

    // Allow 160 KB dynamic LDS (host-side, idempotent, not a stream op).
    (void)hipFuncSetAttribute((const void*)att_fused,
                              hipFuncAttributeMaxDynamicSharedMemorySize, LDS_BYTES);

    convert_weights<<<2048, 256, 0, stream>>>(Wq, Wk, Wv, Wo, wbuf);
    att_fused<<<BB * NBLK, 512, LDS_BYTES, stream>>>(x1, mask, wbuf, bq, bk, bv, bo, out);
}